// Round 3
// baseline (307.781 us; speedup 1.0000x reference)
//
#include <hip/hip_runtime.h>

// Problem constants: x is (256, 3, 224, 224) float32.
#define N_IMG   256
#define HW      (224 * 224)        // 50176
#define CHW     (3 * HW)           // 150528 floats per image
#define V4      (CHW / 4)          // 37632 float4 per image
#define THREADS 256

// Partition: 147 chunks/image, U=7 chunks per block
// -> ABLK=21 blocks/image * 256 images = 5376 blocks, 7 float4 per thread.
#define CHUNKS  (V4 / THREADS)     // 147
#define U       7
#define ABLK    (CHUNKS / U)       // 21 blocks per image

#define MAGS_PER_TF 9

typedef float f4 __attribute__((ext_vector_type(4)));

__device__ __forceinline__ float clip01(float v) {
    return fminf(fmaxf(v, 0.0f), 1.0f);
}

// Single fused kernel. Each block owns a 7*256-float4 slice of one image,
// held entirely in registers. Contrast-applied images (block-uniform
// predicate) compute the image mean cooperatively across that image's 21
// blocks via atomicAdd + arrival counter + spin (the 21 blocks are adjacent
// in dispatch order — always co-residentable; at least one complete image
// is resident at any time, so forward progress is guaranteed).
// Non-contrast blocks never touch the atomics and stream straight through.
__global__ __launch_bounds__(THREADS) void fused_kernel(
        const float* __restrict__ x,
        const int* __restrict__ sample,
        const int* __restrict__ apply_mask,
        float* __restrict__ gsum /* [N_IMG] */,
        int*   __restrict__ gcnt /* [N_IMG] */,
        float* __restrict__ out) {
    const int img = blockIdx.y;
    const int b   = blockIdx.x;            // 0..ABLK-1
    const int s   = sample[img];
    const int tf  = s / MAGS_PER_TF;
    const float mag = (float)(s % MAGS_PER_TF + 1) / 10.0f;
    const bool applied = apply_mask[s] > 0;

    const size_t base = (size_t)img * V4 + (size_t)b * (U * THREADS) + threadIdx.x;
    const f4* xp = (const f4*)x;
    f4*       op = (f4*)out;

    // issue all U loads back-to-back (memory-level parallelism)
    f4 v[U];
#pragma unroll
    for (int k = 0; k < U; ++k) v[k] = xp[base + (size_t)k * THREADS];

    float mean = 0.0f;
    if (applied && tf == 1) {
        // ---- cooperative per-image mean, data already in registers ----
        float ps = 0.0f;
#pragma unroll
        for (int k = 0; k < U; ++k)
            ps += (v[k].x + v[k].y) + (v[k].z + v[k].w);
        // wave (64-lane) shuffle reduction
#pragma unroll
        for (int off = 32; off > 0; off >>= 1)
            ps += __shfl_down(ps, off, 64);

        __shared__ float wsum[THREADS / 64];
        __shared__ float smean;
        if ((threadIdx.x & 63) == 0) wsum[threadIdx.x >> 6] = ps;
        __syncthreads();
        if (threadIdx.x == 0) {
            float t = (wsum[0] + wsum[1]) + (wsum[2] + wsum[3]);
            atomicAdd(&gsum[img], t);            // device-scope by default
            __threadfence();                     // publish sum before arrival
            atomicAdd(&gcnt[img], 1);
            // wait for all ABLK blocks of this image
            while (__hip_atomic_load(&gcnt[img], __ATOMIC_ACQUIRE,
                                     __HIP_MEMORY_SCOPE_AGENT) < ABLK)
                __builtin_amdgcn_s_sleep(2);
            float tot = __hip_atomic_load(&gsum[img], __ATOMIC_RELAXED,
                                          __HIP_MEMORY_SCOPE_AGENT);
            smean = tot / (float)CHW;
        }
        __syncthreads();
        mean = smean;
    }

    if (applied) {
        if (tf == 0) {                   // brightness: clip(x + mag)
#pragma unroll
            for (int k = 0; k < U; ++k) {
                v[k].x = clip01(v[k].x + mag);
                v[k].y = clip01(v[k].y + mag);
                v[k].z = clip01(v[k].z + mag);
                v[k].w = clip01(v[k].w + mag);
            }
        } else if (tf == 1) {            // contrast: clip(mean + (x-mean)*(1+mag))
            const float g = 1.0f + mag;
#pragma unroll
            for (int k = 0; k < U; ++k) {
                v[k].x = clip01(mean + (v[k].x - mean) * g);
                v[k].y = clip01(mean + (v[k].y - mean) * g);
                v[k].z = clip01(mean + (v[k].z - mean) * g);
                v[k].w = clip01(mean + (v[k].w - mean) * g);
            }
        } else if (tf == 2) {            // invert-lerp: (1-mag)*x + mag*(1-x)  (NO clip)
            const float a = 1.0f - mag;
#pragma unroll
            for (int k = 0; k < U; ++k) {
                v[k].x = a * v[k].x + mag * (1.0f - v[k].x);
                v[k].y = a * v[k].y + mag * (1.0f - v[k].y);
                v[k].z = a * v[k].z + mag * (1.0f - v[k].z);
                v[k].w = a * v[k].w + mag * (1.0f - v[k].w);
            }
        } else {                         // gain: clip(x * (1+mag))
            const float g = 1.0f + mag;
#pragma unroll
            for (int k = 0; k < U; ++k) {
                v[k].x = clip01(v[k].x * g);
                v[k].y = clip01(v[k].y * g);
                v[k].z = clip01(v[k].z * g);
                v[k].w = clip01(v[k].w * g);
            }
        }
    }
    // !applied: v[] passes through unchanged

    // plain stores (nt stores regressed round 2: −15 µs store-path hit)
#pragma unroll
    for (int k = 0; k < U; ++k)
        op[base + (size_t)k * THREADS] = v[k];
}

extern "C" void kernel_launch(void* const* d_in, const int* in_sizes, int n_in,
                              void* d_out, int out_size, void* d_ws, size_t ws_size,
                              hipStream_t stream) {
    const float* x          = (const float*)d_in[0];
    const int*   sample     = (const int*)d_in[1];
    const int*   apply_mask = (const int*)d_in[2];
    float*       out        = (float*)d_out;
    float*       gsum       = (float*)d_ws;            // N_IMG floats
    int*         gcnt       = (int*)d_ws + N_IMG;      // N_IMG ints

    // zero the 2 KB of sums+counters (graph-capturable async memset)
    hipMemsetAsync(d_ws, 0, 2 * N_IMG * sizeof(float), stream);

    dim3 grid(ABLK, N_IMG);
    fused_kernel<<<grid, THREADS, 0, stream>>>(x, sample, apply_mask,
                                               gsum, gcnt, out);
}

// Round 4
// 271.921 us; speedup vs baseline: 1.1319x; 1.1319x over previous
//
#include <hip/hip_runtime.h>

// Problem constants: x is (256, 3, 224, 224) float32.
#define N_IMG   256
#define HW      (224 * 224)        // 50176
#define CHW     (3 * HW)           // 150528 floats per image
#define V4      (CHW / 4)          // 37632 float4 per image
#define THREADS 256

// mean_kernel partition: 7 parts * (21 float4/thread * 256 threads) = 37632
#define PARTS       7
#define PART_V4     (V4 / PARTS)        // 5376
#define PER_THREAD  (PART_V4 / THREADS) // 21

// apply_kernel: grid-stride over 147 chunks/image * 256 images = 37632
// chunks; each iteration moves one coalesced 4 KB chunk (256 float4).
#define CHUNKS        (V4 / THREADS)    // 147
#define TOTAL_CHUNKS  (N_IMG * CHUNKS)  // 37632
#define GRID_X        2048              // 8 blocks/CU * 256 CU — full residency

#define MAGS_PER_TF 9

typedef float f4 __attribute__((ext_vector_type(4)));

__device__ __forceinline__ float clip01(float v) {
    return fminf(fmaxf(v, 0.0f), 1.0f);
}

// Kernel 1 (unchanged from the verified round-0 version): per-image mean
// partials — only for images that need it (tf==1 AND apply_mask>0).
__global__ __launch_bounds__(THREADS) void mean_kernel(
        const float* __restrict__ x,
        const int* __restrict__ sample,
        const int* __restrict__ apply_mask,
        float* __restrict__ partials /* [N_IMG][PARTS] */) {
    const int img  = blockIdx.y;
    const int part = blockIdx.x;
    const int s    = sample[img];
    const int tf   = s / MAGS_PER_TF;
    if (tf != 1 || apply_mask[s] <= 0) return;

    const f4* xp = (const f4*)x + (size_t)img * V4 + (size_t)part * PART_V4;
    float sum = 0.0f;
#pragma unroll
    for (int k = 0; k < PER_THREAD; ++k) {
        f4 v = xp[threadIdx.x + k * THREADS];
        sum += (v.x + v.y) + (v.z + v.w);
    }
    // wave (64-lane) shuffle reduction
#pragma unroll
    for (int off = 32; off > 0; off >>= 1)
        sum += __shfl_down(sum, off, 64);

    __shared__ float wsum[THREADS / 64];
    if ((threadIdx.x & 63) == 0) wsum[threadIdx.x >> 6] = sum;
    __syncthreads();
    if (threadIdx.x == 0) {
        float t = (wsum[0] + wsum[1]) + (wsum[2] + wsum[3]);
        partials[img * PARTS + part] = t;
    }
}

// Kernel 2: grid-stride copy-structure (the measured-fast streaming shape on
// this chip): 2048 long-lived blocks, one load->transform->store of a 4 KB
// chunk per iteration, block preamble amortized over ~18 iterations.
// All control flow is block-uniform (chunk id depends only on blockIdx +
// iteration). Plain stores; no register batching (both regressed earlier).
__global__ __launch_bounds__(THREADS) void apply_kernel(
        const float* __restrict__ x,
        const int* __restrict__ sample,
        const int* __restrict__ apply_mask,
        const float* __restrict__ partials,
        float* __restrict__ out) {
    const f4* xp = (const f4*)x;
    f4*       op = (f4*)out;

    for (int c = blockIdx.x; c < TOTAL_CHUNKS; c += GRID_X) {
        const int img   = c / CHUNKS;          // uniform scalar math
        const int chunk = c - img * CHUNKS;
        const int s     = sample[img];
        const int tf    = s / MAGS_PER_TF;
        const float mag = (float)(s % MAGS_PER_TF + 1) / 10.0f;
        const bool applied = apply_mask[s] > 0;

        const size_t idx = (size_t)img * V4 + (size_t)chunk * THREADS + threadIdx.x;
        f4 v = xp[idx];
        f4 r;

        if (!applied) {
            r = v;
        } else if (tf == 0) {            // brightness: clip(x + mag)
            r.x = clip01(v.x + mag);
            r.y = clip01(v.y + mag);
            r.z = clip01(v.z + mag);
            r.w = clip01(v.w + mag);
        } else if (tf == 1) {            // contrast: clip(mean + (x-mean)*(1+mag))
            float mean = 0.0f;
#pragma unroll
            for (int p = 0; p < PARTS; ++p) mean += partials[img * PARTS + p];
            mean /= (float)CHW;
            const float g = 1.0f + mag;
            r.x = clip01(mean + (v.x - mean) * g);
            r.y = clip01(mean + (v.y - mean) * g);
            r.z = clip01(mean + (v.z - mean) * g);
            r.w = clip01(mean + (v.w - mean) * g);
        } else if (tf == 2) {            // invert-lerp: (1-mag)*x + mag*(1-x)  (NO clip)
            const float a = 1.0f - mag;
            r.x = a * v.x + mag * (1.0f - v.x);
            r.y = a * v.y + mag * (1.0f - v.y);
            r.z = a * v.z + mag * (1.0f - v.z);
            r.w = a * v.w + mag * (1.0f - v.w);
        } else {                         // gain: clip(x * (1+mag))
            const float g = 1.0f + mag;
            r.x = clip01(v.x * g);
            r.y = clip01(v.y * g);
            r.z = clip01(v.z * g);
            r.w = clip01(v.w * g);
        }

        op[idx] = r;
    }
}

extern "C" void kernel_launch(void* const* d_in, const int* in_sizes, int n_in,
                              void* d_out, int out_size, void* d_ws, size_t ws_size,
                              hipStream_t stream) {
    const float* x          = (const float*)d_in[0];
    const int*   sample     = (const int*)d_in[1];
    const int*   apply_mask = (const int*)d_in[2];
    float*       out        = (float*)d_out;
    float*       partials   = (float*)d_ws;   // N_IMG * PARTS floats = 7 KiB

    dim3 mgrid(PARTS, N_IMG);
    mean_kernel<<<mgrid, THREADS, 0, stream>>>(x, sample, apply_mask, partials);

    apply_kernel<<<dim3(GRID_X), dim3(THREADS), 0, stream>>>(
        x, sample, apply_mask, partials, out);
}

// Round 5
// 271.648 us; speedup vs baseline: 1.1330x; 1.0010x over previous
//
#include <hip/hip_runtime.h>

// Problem constants: x is (256, 3, 224, 224) float32.
#define N_IMG   256
#define HW      (224 * 224)        // 50176
#define CHW     (3 * HW)           // 150528 floats per image
#define V4      (CHW / 4)          // 37632 float4 per image
#define THREADS 256

// mean_kernel partition: 7 parts * (21 float4/thread * 256 threads) = 37632
#define PARTS       7
#define PART_V4     (V4 / PARTS)        // 5376
#define PER_THREAD  (PART_V4 / THREADS) // 21

// apply_kernel partition: 147 chunks/image, U=3 chunks per block
// -> ABLK=49 blocks/image * 256 images = 12544 one-shot blocks,
//    3 float4 per thread (loads issued back-to-back for MLP, plain stores).
#define CHUNKS  (V4 / THREADS)     // 147
#define U       3
#define ABLK    (CHUNKS / U)       // 49 blocks per image

#define MAGS_PER_TF 9

typedef float f4 __attribute__((ext_vector_type(4)));

__device__ __forceinline__ float clip01(float v) {
    return fminf(fmaxf(v, 0.0f), 1.0f);
}

// Kernel 1 (unchanged, verified): per-image mean partials — only for images
// that need it (tf==1 AND apply_mask>0); others early-exit.
__global__ __launch_bounds__(THREADS) void mean_kernel(
        const float* __restrict__ x,
        const int* __restrict__ sample,
        const int* __restrict__ apply_mask,
        float* __restrict__ partials /* [N_IMG][PARTS] */) {
    const int img  = blockIdx.y;
    const int part = blockIdx.x;
    const int s    = sample[img];
    const int tf   = s / MAGS_PER_TF;
    if (tf != 1 || apply_mask[s] <= 0) return;

    const f4* xp = (const f4*)x + (size_t)img * V4 + (size_t)part * PART_V4;
    float sum = 0.0f;
#pragma unroll
    for (int k = 0; k < PER_THREAD; ++k) {
        f4 v = xp[threadIdx.x + k * THREADS];
        sum += (v.x + v.y) + (v.z + v.w);
    }
    // wave (64-lane) shuffle reduction
#pragma unroll
    for (int off = 32; off > 0; off >>= 1)
        sum += __shfl_down(sum, off, 64);

    __shared__ float wsum[THREADS / 64];
    if ((threadIdx.x & 63) == 0) wsum[threadIdx.x >> 6] = sum;
    __syncthreads();
    if (threadIdx.x == 0) {
        float t = (wsum[0] + wsum[1]) + (wsum[2] + wsum[3]);
        partials[img * PARTS + part] = t;
    }
}

// Kernel 2: R0's one-shot-block structure (the measured-best at ~74 µs for
// the pair) with exactly ONE change: U=3 float4 per thread, loads issued
// back-to-back (matches the 6.29 TB/s copy-µbench shape). Plain stores —
// nt stores cost ~20 µs in round 2. Block-uniform branches.
__global__ __launch_bounds__(THREADS) void apply_kernel(
        const float* __restrict__ x,
        const int* __restrict__ sample,
        const int* __restrict__ apply_mask,
        const float* __restrict__ partials,
        float* __restrict__ out) {
    const int img = blockIdx.y;
    const int b   = blockIdx.x;            // 0..ABLK-1
    const int s   = sample[img];
    const int tf  = s / MAGS_PER_TF;
    const float mag = (float)(s % MAGS_PER_TF + 1) / 10.0f;
    const bool applied = apply_mask[s] > 0;

    const size_t base = (size_t)img * V4 + (size_t)b * (U * THREADS) + threadIdx.x;
    const f4* xp = (const f4*)x;
    f4*       op = (f4*)out;

    // issue all U loads back-to-back (memory-level parallelism)
    f4 v[U];
#pragma unroll
    for (int k = 0; k < U; ++k) v[k] = xp[base + (size_t)k * THREADS];

    if (applied) {
        if (tf == 0) {                   // brightness: clip(x + mag)
#pragma unroll
            for (int k = 0; k < U; ++k) {
                v[k].x = clip01(v[k].x + mag);
                v[k].y = clip01(v[k].y + mag);
                v[k].z = clip01(v[k].z + mag);
                v[k].w = clip01(v[k].w + mag);
            }
        } else if (tf == 1) {            // contrast: clip(mean + (x-mean)*(1+mag))
            float mean = 0.0f;
#pragma unroll
            for (int p = 0; p < PARTS; ++p) mean += partials[img * PARTS + p];
            mean /= (float)CHW;
            const float g = 1.0f + mag;
#pragma unroll
            for (int k = 0; k < U; ++k) {
                v[k].x = clip01(mean + (v[k].x - mean) * g);
                v[k].y = clip01(mean + (v[k].y - mean) * g);
                v[k].z = clip01(mean + (v[k].z - mean) * g);
                v[k].w = clip01(mean + (v[k].w - mean) * g);
            }
        } else if (tf == 2) {            // invert-lerp: (1-mag)*x + mag*(1-x)  (NO clip)
            const float a = 1.0f - mag;
#pragma unroll
            for (int k = 0; k < U; ++k) {
                v[k].x = a * v[k].x + mag * (1.0f - v[k].x);
                v[k].y = a * v[k].y + mag * (1.0f - v[k].y);
                v[k].z = a * v[k].z + mag * (1.0f - v[k].z);
                v[k].w = a * v[k].w + mag * (1.0f - v[k].w);
            }
        } else {                         // gain: clip(x * (1+mag))
            const float g = 1.0f + mag;
#pragma unroll
            for (int k = 0; k < U; ++k) {
                v[k].x = clip01(v[k].x * g);
                v[k].y = clip01(v[k].y * g);
                v[k].z = clip01(v[k].z * g);
                v[k].w = clip01(v[k].w * g);
            }
        }
    }
    // !applied: v[] passes through unchanged

#pragma unroll
    for (int k = 0; k < U; ++k)
        op[base + (size_t)k * THREADS] = v[k];
}

extern "C" void kernel_launch(void* const* d_in, const int* in_sizes, int n_in,
                              void* d_out, int out_size, void* d_ws, size_t ws_size,
                              hipStream_t stream) {
    const float* x          = (const float*)d_in[0];
    const int*   sample     = (const int*)d_in[1];
    const int*   apply_mask = (const int*)d_in[2];
    float*       out        = (float*)d_out;
    float*       partials   = (float*)d_ws;   // N_IMG * PARTS floats = 7 KiB

    dim3 mgrid(PARTS, N_IMG);
    mean_kernel<<<mgrid, THREADS, 0, stream>>>(x, sample, apply_mask, partials);

    dim3 agrid(ABLK, N_IMG);
    apply_kernel<<<agrid, THREADS, 0, stream>>>(x, sample, apply_mask, partials, out);
}

// Round 6
// 260.707 us; speedup vs baseline: 1.1806x; 1.0420x over previous
//
#include <hip/hip_runtime.h>

// Problem constants: x is (256, 3, 224, 224) float32.
#define N_IMG   256
#define HW      (224 * 224)        // 50176
#define CHW     (3 * HW)           // 150528 floats per image
#define V4      (CHW / 4)          // 37632 float4 per image
#define THREADS 256

// mean_kernel partition: 7 parts * (21 float4/thread * 256 threads) = 37632
#define PARTS       7
#define PART_V4     (V4 / PARTS)        // 5376
#define PER_THREAD  (PART_V4 / THREADS) // 21

// apply_kernel partition (R0 champion shape): 147 chunks/image, one 256-f4
// chunk per one-shot block -> 37632 blocks, 1 float4 per thread.
#define CHUNKS  (V4 / THREADS)     // 147

#define MAGS_PER_TF 9

typedef float f4 __attribute__((ext_vector_type(4)));

__device__ __forceinline__ float clip01(float v) {
    return fminf(fmaxf(v, 0.0f), 1.0f);
}

// Workspace layout:
//   ws[0 .. 255]          : params[img] = float4(mag, 1+mag, 1-mag, code)
//                           code = tf (0..3) if applied else -1 (as float)
//   ws[1024 ...]          : partials[img][PARTS]
// Kernel 1: per-image params (part-0 blocks) + mean partials (contrast-
// applied images only; others early-exit AFTER the param write).
__global__ __launch_bounds__(THREADS) void mean_kernel(
        const float* __restrict__ x,
        const int* __restrict__ sample,
        const int* __restrict__ apply_mask,
        float* __restrict__ ws) {
    const int img  = blockIdx.y;
    const int part = blockIdx.x;
    const int s    = sample[img];
    const int tf   = s / MAGS_PER_TF;
    const bool applied = apply_mask[s] > 0;

    if (part == 0 && threadIdx.x == 0) {
        const float mag = (float)(s % MAGS_PER_TF + 1) / 10.0f;
        f4 p;
        p.x = mag;
        p.y = 1.0f + mag;
        p.z = 1.0f - mag;
        p.w = applied ? (float)tf : -1.0f;   // small ints exact in float
        ((f4*)ws)[img] = p;
    }
    // early-exit path: in the non-contrast case ALL threads return (no
    // barrier reached); in the contrast case NO thread returns. Safe.
    if (tf != 1 || !applied) return;

    const f4* xp = (const f4*)x + (size_t)img * V4 + (size_t)part * PART_V4;
    float sum = 0.0f;
#pragma unroll
    for (int k = 0; k < PER_THREAD; ++k) {
        f4 v = xp[threadIdx.x + k * THREADS];
        sum += (v.x + v.y) + (v.z + v.w);
    }
    // wave (64-lane) shuffle reduction
#pragma unroll
    for (int off = 32; off > 0; off >>= 1)
        sum += __shfl_down(sum, off, 64);

    __shared__ float wsum[THREADS / 64];
    if ((threadIdx.x & 63) == 0) wsum[threadIdx.x >> 6] = sum;
    __syncthreads();
    if (threadIdx.x == 0) {
        float t = (wsum[0] + wsum[1]) + (wsum[2] + wsum[3]);
        ws[1024 + img * PARTS + part] = t;
    }
}

// Kernel 2: R0 champion memory shape (1 float4/thread, one-shot blocks,
// plain stores) with the per-wave scalar preamble collapsed to a single
// uniform 16B load from the L2-hot params table. No sample/apply_mask
// loads, no int div/mod in the hot kernel; partials touched only by
// contrast blocks (~12.5%).
__global__ __launch_bounds__(THREADS) void apply_kernel(
        const float* __restrict__ x,
        const float* __restrict__ ws,
        float* __restrict__ out) {
    const int img   = blockIdx.y;
    const int chunk = blockIdx.x;

    const f4 P = ((const f4*)ws)[img];    // uniform -> s_load_dwordx4
    const int code = (int)P.w;            // -1 pass, 0..3 transform

    const size_t idx = (size_t)img * V4 + (size_t)chunk * THREADS + threadIdx.x;
    const f4* xp = (const f4*)x;
    f4*       op = (f4*)out;

    f4 v = xp[idx];
    f4 r;

    if (code < 0) {                  // not applied: passthrough
        r = v;
    } else if (code == 0) {          // brightness: clip(x + mag)
        r.x = clip01(v.x + P.x);
        r.y = clip01(v.y + P.x);
        r.z = clip01(v.z + P.x);
        r.w = clip01(v.w + P.x);
    } else if (code == 1) {          // contrast: clip(mean + (x-mean)*(1+mag))
        float mean = 0.0f;
#pragma unroll
        for (int p = 0; p < PARTS; ++p) mean += ws[1024 + img * PARTS + p];
        mean /= (float)CHW;
        const float g = P.y;
        r.x = clip01(mean + (v.x - mean) * g);
        r.y = clip01(mean + (v.y - mean) * g);
        r.z = clip01(mean + (v.z - mean) * g);
        r.w = clip01(mean + (v.w - mean) * g);
    } else if (code == 2) {          // invert-lerp: (1-mag)*x + mag*(1-x)  (NO clip)
        const float a = P.z, mag = P.x;
        r.x = a * v.x + mag * (1.0f - v.x);
        r.y = a * v.y + mag * (1.0f - v.y);
        r.z = a * v.z + mag * (1.0f - v.z);
        r.w = a * v.w + mag * (1.0f - v.w);
    } else {                         // gain: clip(x * (1+mag))
        const float g = P.y;
        r.x = clip01(v.x * g);
        r.y = clip01(v.y * g);
        r.z = clip01(v.z * g);
        r.w = clip01(v.w * g);
    }

    op[idx] = r;
}

extern "C" void kernel_launch(void* const* d_in, const int* in_sizes, int n_in,
                              void* d_out, int out_size, void* d_ws, size_t ws_size,
                              hipStream_t stream) {
    const float* x          = (const float*)d_in[0];
    const int*   sample     = (const int*)d_in[1];
    const int*   apply_mask = (const int*)d_in[2];
    float*       out        = (float*)d_out;
    float*       ws         = (float*)d_ws;   // params (4 KiB) + partials (7 KiB)

    dim3 mgrid(PARTS, N_IMG);
    mean_kernel<<<mgrid, THREADS, 0, stream>>>(x, sample, apply_mask, ws);

    dim3 agrid(CHUNKS, N_IMG);
    apply_kernel<<<agrid, THREADS, 0, stream>>>(x, ws, out);
}